// Round 2
// baseline (315.145 us; speedup 1.0000x reference)
//
#include <hip/hip_runtime.h>

// SSIM (32,3,512,512) fp32, 11x11 gaussian sigma=1.5 VALID, scalar mean.
// Wave-autonomous design: each 64-lane wave owns (image, 128-col strip,
// 63-row band). Vertical conv in a rolling 12-row register window
// (2 output rows per iteration so products amortize); horizontal conv via
// __shfl from 5 neighbor lanes (no LDS tiles, no __syncthreads anywhere).
// Per-wave partial -> plain store -> tiny reduce kernel.

namespace {
constexpr int IMG_H = 512, IMG_W = 512;
constexpr int OUT_H = 502, OUT_W = 502;
constexpr int NIMG   = 96;            // B*C
constexpr int NSTRIP = 5;             // col strips start at 100*s, outputs [100s, min(100s+100,502))
constexpr int NBAND  = 8;             // row bands of 63 (last 61)
constexpr int RB     = 63;
constexpr int NTASK  = NIMG * NSTRIP * NBAND;   // 3840 waves
constexpr double TOTAL = 24192384.0;  // 96*502*502

// exp(-k^2/4.5), double, normalized at compile time (validated: absmax 0.0 in R1)
constexpr double U0 = 0.0038659201;
constexpr double U1 = 0.0285655007;
constexpr double U2 = 0.1353352832366127;
constexpr double U3 = 0.4111122898;
constexpr double U4 = 0.8007374026;
constexpr double SS = 1.0 + 2.0 * (U0 + U1 + U2 + U3 + U4);
}

#define G_DEF const float g[11] = { \
    (float)(U0/SS), (float)(U1/SS), (float)(U2/SS), (float)(U3/SS), (float)(U4/SS), \
    (float)(1.0/SS), \
    (float)(U4/SS), (float)(U3/SS), (float)(U2/SS), (float)(U1/SS), (float)(U0/SS) }

// One output row: h-conv of 5 v-stats via lane shuffles, SSIM for this
// lane's two output columns, masked accumulate.
__device__ __forceinline__ void hssim(const float2 v[5], const float g[11], int lane,
                                      bool va, bool vb, float& acc0, float& acc1)
{
    float h0[5], h1[5];
    #pragma unroll
    for (int i = 0; i < 5; ++i) {
        float a[12];
        a[0] = v[i].x; a[1] = v[i].y;
        #pragma unroll
        for (int d = 1; d <= 5; ++d) {
            a[2*d]     = __shfl(v[i].x, lane + d, 64);
            a[2*d + 1] = __shfl(v[i].y, lane + d, 64);
        }
        float s0 = 0.f, s1 = 0.f;
        #pragma unroll
        for (int k = 0; k < 11; ++k) {
            s0 = fmaf(g[k], a[k],     s0);
            s1 = fmaf(g[k], a[k + 1], s1);
        }
        h0[i] = s0; h1[i] = s1;
    }
    constexpr float C1 = 1e-4f, C2 = 9e-4f;
    {
        float mu1 = h0[0], mu2 = h0[1];
        float mu11 = mu1*mu1, mu22 = mu2*mu2, mu12 = mu1*mu2;
        float s1 = h0[2] - mu11, s2 = h0[3] - mu22, s12 = h0[4] - mu12;
        float num = fmaf(2.f, mu12, C1) * fmaf(2.f, s12, C2);
        float den = (mu11 + mu22 + C1) * (s1 + s2 + C2);
        float rc = __builtin_amdgcn_rcpf(den);
        rc = rc * fmaf(-den, rc, 2.f);        // one Newton step
        float val = num * rc;
        acc0 += va ? val : 0.f;               // cndmask: garbage/Inf in halo lanes never enters acc
    }
    {
        float mu1 = h1[0], mu2 = h1[1];
        float mu11 = mu1*mu1, mu22 = mu2*mu2, mu12 = mu1*mu2;
        float s1 = h1[2] - mu11, s2 = h1[3] - mu22, s12 = h1[4] - mu12;
        float num = fmaf(2.f, mu12, C1) * fmaf(2.f, s12, C2);
        float den = (mu11 + mu22 + C1) * (s1 + s2 + C2);
        float rc = __builtin_amdgcn_rcpf(den);
        rc = rc * fmaf(-den, rc, 2.f);
        float val = num * rc;
        acc1 += vb ? val : 0.f;
    }
}

__global__ __launch_bounds__(64, 3) void ssim_main(const float* __restrict__ img1,
                                                   const float* __restrict__ img2,
                                                   float* __restrict__ partial)
{
    G_DEF;
    const int t    = threadIdx.x;                 // lane 0..63
    const int task = blockIdx.x;
    const int z    = task / (NSTRIP * NBAND);
    const int rem  = task - z * (NSTRIP * NBAND);
    const int s    = rem / NBAND;
    const int b    = rem - s * NBAND;

    const int lo = 100 * s;
    const int hi = (s == NSTRIP - 1) ? OUT_W : lo + 100;
    const int r0 = RB * b;
    const int r1 = min(r0 + RB, OUT_H);

    const int  o0 = lo + 2 * t;                   // this lane's first output col
    const bool va = (o0     < hi);
    const bool vb = (o0 + 1 < hi);

    const int col = min(o0, IMG_W - 2);           // clamp only matters for strip 4 halo lanes
    const float* p1 = img1 + (size_t)z * (IMG_H * IMG_W) + col;
    const float* p2 = img2 + (size_t)z * (IMG_H * IMG_W) + col;

    // rolling window: input rows r..r+11 (12 rows covers 2 output rows)
    float2 wx[12], wy[12];
    #pragma unroll
    for (int j = 0; j < 12; ++j) {
        wx[j] = *(const float2*)(p1 + (size_t)(r0 + j) * IMG_W);
        wy[j] = *(const float2*)(p2 + (size_t)(r0 + j) * IMG_W);
    }

    float acc0 = 0.f, acc1 = 0.f;

    int r = r0;
    for (; r + 1 < r1; r += 2) {
        // prefetch the next pair's two new rows (clamped; row 512 would be OOB)
        const int ra = min(r + 12, IMG_H - 1);
        const int rb2 = min(r + 13, IMG_H - 1);
        float2 nx0 = *(const float2*)(p1 + (size_t)ra  * IMG_W);
        float2 ny0 = *(const float2*)(p2 + (size_t)ra  * IMG_W);
        float2 nx1 = *(const float2*)(p1 + (size_t)rb2 * IMG_W);
        float2 ny1 = *(const float2*)(p2 + (size_t)rb2 * IMG_W);

        // vertical conv: row r uses taps k=0..10, row r+1 uses k=1..11;
        // per-row products computed once per window slot, shared by both rows
        float2 vA[5], vB[5];
        #pragma unroll
        for (int i = 0; i < 5; ++i) { vA[i] = make_float2(0.f, 0.f); vB[i] = make_float2(0.f, 0.f); }
        #pragma unroll
        for (int k = 0; k < 12; ++k) {
            float2 x = wx[k], y = wy[k];
            float xx0 = x.x*x.x, xx1 = x.y*x.y;
            float yy0 = y.x*y.x, yy1 = y.y*y.y;
            float xy0 = x.x*y.x, xy1 = x.y*y.y;
            if (k < 11) {
                float gk = g[k];
                vA[0].x = fmaf(gk, x.x, vA[0].x); vA[0].y = fmaf(gk, x.y, vA[0].y);
                vA[1].x = fmaf(gk, y.x, vA[1].x); vA[1].y = fmaf(gk, y.y, vA[1].y);
                vA[2].x = fmaf(gk, xx0, vA[2].x); vA[2].y = fmaf(gk, xx1, vA[2].y);
                vA[3].x = fmaf(gk, yy0, vA[3].x); vA[3].y = fmaf(gk, yy1, vA[3].y);
                vA[4].x = fmaf(gk, xy0, vA[4].x); vA[4].y = fmaf(gk, xy1, vA[4].y);
            }
            if (k >= 1) {
                float gk = g[k - 1];
                vB[0].x = fmaf(gk, x.x, vB[0].x); vB[0].y = fmaf(gk, x.y, vB[0].y);
                vB[1].x = fmaf(gk, y.x, vB[1].x); vB[1].y = fmaf(gk, y.y, vB[1].y);
                vB[2].x = fmaf(gk, xx0, vB[2].x); vB[2].y = fmaf(gk, xx1, vB[2].y);
                vB[3].x = fmaf(gk, yy0, vB[3].x); vB[3].y = fmaf(gk, yy1, vB[3].y);
                vB[4].x = fmaf(gk, xy0, vB[4].x); vB[4].y = fmaf(gk, xy1, vB[4].y);
            }
        }

        hssim(vA, g, t, va, vb, acc0, acc1);
        hssim(vB, g, t, va, vb, acc0, acc1);

        // slide window by 2
        #pragma unroll
        for (int k = 0; k < 10; ++k) { wx[k] = wx[k + 2]; wy[k] = wy[k + 2]; }
        wx[10] = nx0; wy[10] = ny0; wx[11] = nx1; wy[11] = ny1;
    }

    if (r < r1) {  // odd tail row: taps wx[0..10]
        float2 vA[5];
        #pragma unroll
        for (int i = 0; i < 5; ++i) vA[i] = make_float2(0.f, 0.f);
        #pragma unroll
        for (int k = 0; k < 11; ++k) {
            float2 x = wx[k], y = wy[k];
            float gk = g[k];
            vA[0].x = fmaf(gk, x.x, vA[0].x);       vA[0].y = fmaf(gk, x.y, vA[0].y);
            vA[1].x = fmaf(gk, y.x, vA[1].x);       vA[1].y = fmaf(gk, y.y, vA[1].y);
            vA[2].x = fmaf(gk, x.x*x.x, vA[2].x);   vA[2].y = fmaf(gk, x.y*x.y, vA[2].y);
            vA[3].x = fmaf(gk, y.x*y.x, vA[3].x);   vA[3].y = fmaf(gk, y.y*y.y, vA[3].y);
            vA[4].x = fmaf(gk, x.x*y.x, vA[4].x);   vA[4].y = fmaf(gk, x.y*y.y, vA[4].y);
        }
        hssim(vA, g, t, va, vb, acc0, acc1);
    }

    // wave reduction -> one plain store per wave (no atomics, no init needed)
    float local = acc0 + acc1;
    #pragma unroll
    for (int off = 32; off > 0; off >>= 1) local += __shfl_down(local, off, 64);
    if (t == 0) partial[task] = local;
}

__global__ void ssim_fin(const float* __restrict__ partial, float* __restrict__ out)
{
    __shared__ double sd[256];
    double sum = 0.0;
    for (int i = threadIdx.x; i < NTASK; i += 256) sum += (double)partial[i];
    sd[threadIdx.x] = sum;
    __syncthreads();
    for (int w = 128; w > 0; w >>= 1) {
        if (threadIdx.x < w) sd[threadIdx.x] += sd[threadIdx.x + w];
        __syncthreads();
    }
    if (threadIdx.x == 0) out[0] = (float)(sd[0] / TOTAL);
}

extern "C" void kernel_launch(void* const* d_in, const int* in_sizes, int n_in,
                              void* d_out, int out_size, void* d_ws, size_t ws_size,
                              hipStream_t stream)
{
    (void)in_sizes; (void)n_in; (void)out_size; (void)ws_size;
    const float* img1 = (const float*)d_in[0];
    const float* img2 = (const float*)d_in[1];
    float* partial = (float*)d_ws;

    hipLaunchKernelGGL(ssim_main, dim3(NTASK), dim3(64), 0, stream, img1, img2, partial);
    hipLaunchKernelGGL(ssim_fin, dim3(1), dim3(256), 0, stream, partial, (float*)d_out);
}

// Round 3
// 302.871 us; speedup vs baseline: 1.0405x; 1.0405x over previous
//
#include <hip/hip_runtime.h>

// SSIM (32,3,512,512) fp32, 11x11 gaussian sigma=1.5 VALID, scalar mean.
// R1 structure (fused separable conv: v-pass in registers, 5-ch v-stats in
// LDS, h-pass 8 cols/thread) with R3 fixes:
//  - QR=3, BUFW=528, RPB=32 -> LDS 31.7KB -> 5 blocks/CU, grid 1536 fills it
//  - read-pattern swizzle s(c4)=c4^((c4>>3)&1): stride-2 float4 reads tile
//    all 32 banks (old swizzle left half the banks idle -> 9.6M conflict cyc)
//  - Newton-rcp SSIM divide, per-block partial store + reduce kernel

namespace {
constexpr int IMG_H = 512, IMG_W = 512;
constexpr int OUT_H = 502, OUT_W = 502;
constexpr int NIMG  = 96;             // B*C
constexpr int RPB   = 32;             // output rows per block
constexpr int NBAND = 16;             // ceil(502/32)
constexpr int QR    = 3;              // output rows per inner iteration
constexpr int BUFW  = 528;            // 132 float4 slots (512 data + halo/pad)
constexpr int NTASK = NBAND * NIMG;   // 1536 blocks
constexpr double TOTAL = 24192384.0;  // 96*502*502

// exp(-k^2/4.5), double, normalized at compile time (absmax 0.0 in R1/R2)
constexpr double U0 = 0.0038659201;
constexpr double U1 = 0.0285655007;
constexpr double U2 = 0.1353352832366127;
constexpr double U3 = 0.4111122898;
constexpr double U4 = 0.8007374026;
constexpr double SS = 1.0 + 2.0 * (U0 + U1 + U2 + U3 + U4);
}

__device__ __forceinline__ int sw(int c4) { return c4 ^ ((c4 >> 3) & 1); }

__device__ __forceinline__ float2 f2fma(float w, float2 a, float2 c) {
    return make_float2(fmaf(w, a.x, c.x), fmaf(w, a.y, c.y));
}

__global__ __launch_bounds__(256, 5) void ssim_main(const float* __restrict__ img1,
                                                    const float* __restrict__ img2,
                                                    float* __restrict__ partial)
{
    __shared__ __align__(16) float vrow[QR][5][BUFW];
    __shared__ float red[4];

    const float g[11] = {
        (float)(U0/SS), (float)(U1/SS), (float)(U2/SS), (float)(U3/SS), (float)(U4/SS),
        (float)(1.0/SS),
        (float)(U4/SS), (float)(U3/SS), (float)(U2/SS), (float)(U1/SS), (float)(U0/SS)
    };
    constexpr float C1 = 1e-4f, C2 = 9e-4f;

    const int t   = threadIdx.x;
    const int z   = blockIdx.y;
    const int oy0 = blockIdx.x * RPB;
    const int row_end = min(oy0 + RPB, OUT_H);

    const float* p1 = img1 + (size_t)z * (IMG_H * IMG_W);
    const float* p2 = img2 + (size_t)z * (IMG_H * IMG_W);

    // phase-V: thread owns input cols 2t, 2t+1
    const int woff = (sw(t >> 1) << 2) + ((t & 1) << 1);

    // phase-H: hq = row-in-group (t>>6, rows 0..2 active), 8-col group at cb
    const int hq = t >> 6;
    const int hl = t & 63;
    const int cb = hl << 3;
    int roff[5];
    #pragma unroll
    for (int k = 0; k < 5; ++k) roff[k] = sw((cb >> 2) + k) << 2;

    float local = 0.f;

    for (int r0 = oy0; r0 < row_end; r0 += QR) {
        // ------------- phase V: vertical 11-tap conv, registers -------------
        float2 xr[QR + 10], yr[QR + 10];
        #pragma unroll
        for (int j = 0; j < QR + 10; ++j) {
            int row = r0 + j;
            row = row < IMG_H ? row : IMG_H - 1;   // tail clamp; unused by valid outputs
            xr[j] = *(const float2*)(p1 + (size_t)row * IMG_W + 2 * t);
            yr[j] = *(const float2*)(p2 + (size_t)row * IMG_W + 2 * t);
        }
        float2 vm1[QR], vm2[QR], v11[QR], v22[QR], v12[QR];
        #pragma unroll
        for (int q = 0; q < QR; ++q) {
            vm1[q] = make_float2(0.f, 0.f); vm2[q] = make_float2(0.f, 0.f);
            v11[q] = make_float2(0.f, 0.f); v22[q] = make_float2(0.f, 0.f);
            v12[q] = make_float2(0.f, 0.f);
        }
        #pragma unroll
        for (int j = 0; j < QR + 10; ++j) {
            float2 x = xr[j], y = yr[j];
            float2 xx = make_float2(x.x * x.x, x.y * x.y);
            float2 yy = make_float2(y.x * y.x, y.y * y.y);
            float2 xy = make_float2(x.x * y.x, x.y * y.y);
            #pragma unroll
            for (int q = 0; q < QR; ++q) {
                int k = j - q;
                if (k >= 0 && k < 11) {
                    float w = g[k];
                    vm1[q] = f2fma(w, x,  vm1[q]);
                    vm2[q] = f2fma(w, y,  vm2[q]);
                    v11[q] = f2fma(w, xx, v11[q]);
                    v22[q] = f2fma(w, yy, v22[q]);
                    v12[q] = f2fma(w, xy, v12[q]);
                }
            }
        }
        __syncthreads();   // previous iteration's phase-H reads complete
        #pragma unroll
        for (int q = 0; q < QR; ++q) {
            *(float2*)&vrow[q][0][woff] = vm1[q];
            *(float2*)&vrow[q][1][woff] = vm2[q];
            *(float2*)&vrow[q][2][woff] = v11[q];
            *(float2*)&vrow[q][3][woff] = v22[q];
            *(float2*)&vrow[q][4][woff] = v12[q];
        }
        __syncthreads();

        // ------------- phase H: horizontal 11-tap conv + SSIM -------------
        const int rr = r0 + hq;
        if (hq < QR && rr < row_end && cb < OUT_W) {
            float aa[5][8];
            #pragma unroll
            for (int ch = 0; ch < 5; ++ch) {
                const float* bc = &vrow[hq][ch][0];
                float f[20];
                #pragma unroll
                for (int k = 0; k < 5; ++k) {
                    float4 v = *(const float4*)(bc + roff[k]);
                    f[4*k+0] = v.x; f[4*k+1] = v.y; f[4*k+2] = v.z; f[4*k+3] = v.w;
                }
                #pragma unroll
                for (int j = 0; j < 8; ++j) {
                    float s = 0.f;
                    #pragma unroll
                    for (int k = 0; k < 11; ++k) s = fmaf(g[k], f[j + k], s);
                    aa[ch][j] = s;
                }
            }
            #pragma unroll
            for (int j = 0; j < 8; ++j) {
                if (cb + j < OUT_W) {
                    float mu1 = aa[0][j], mu2 = aa[1][j];
                    float mu11 = mu1 * mu1, mu22 = mu2 * mu2, mu12 = mu1 * mu2;
                    float s1  = aa[2][j] - mu11;
                    float s2  = aa[3][j] - mu22;
                    float s12 = aa[4][j] - mu12;
                    float num = fmaf(2.f, mu12, C1) * fmaf(2.f, s12, C2);
                    float den = (mu11 + mu22 + C1) * (s1 + s2 + C2);
                    float rc  = __builtin_amdgcn_rcpf(den);
                    rc = rc * fmaf(-den, rc, 2.f);          // one Newton step
                    local += num * rc;
                }
            }
        }
    }

    // ---------- reduction: wave shuffle -> LDS -> one store per block ----------
    #pragma unroll
    for (int off = 32; off > 0; off >>= 1) local += __shfl_down(local, off, 64);
    if ((t & 63) == 0) red[t >> 6] = local;
    __syncthreads();
    if (t == 0)
        partial[blockIdx.y * NBAND + blockIdx.x] = red[0] + red[1] + red[2] + red[3];
}

__global__ void ssim_fin(const float* __restrict__ partial, float* __restrict__ out)
{
    __shared__ double sd[256];
    double sum = 0.0;
    for (int i = threadIdx.x; i < NTASK; i += 256) sum += (double)partial[i];
    sd[threadIdx.x] = sum;
    __syncthreads();
    for (int w = 128; w > 0; w >>= 1) {
        if (threadIdx.x < w) sd[threadIdx.x] += sd[threadIdx.x + w];
        __syncthreads();
    }
    if (threadIdx.x == 0) out[0] = (float)(sd[0] / TOTAL);
}

extern "C" void kernel_launch(void* const* d_in, const int* in_sizes, int n_in,
                              void* d_out, int out_size, void* d_ws, size_t ws_size,
                              hipStream_t stream)
{
    (void)in_sizes; (void)n_in; (void)out_size; (void)ws_size;
    const float* img1 = (const float*)d_in[0];
    const float* img2 = (const float*)d_in[1];
    float* partial = (float*)d_ws;

    hipLaunchKernelGGL(ssim_main, dim3(NBAND, NIMG), dim3(256), 0, stream,
                       img1, img2, partial);
    hipLaunchKernelGGL(ssim_fin, dim3(1), dim3(256), 0, stream,
                       partial, (float*)d_out);
}

// Round 4
// 275.188 us; speedup vs baseline: 1.1452x; 1.1006x over previous
//
#include <hip/hip_runtime.h>

// SSIM (32,3,512,512) fp32, 11x11 gaussian sigma=1.5 VALID, scalar mean.
// Fused separable conv: v-pass in registers, 5-ch v-stats in LDS (swizzled),
// h-pass 8 cols/thread, SSIM + mean fused.
// R4: __launch_bounds__(256,4). R3's (256,5) capped VGPRs at 48 -> the
// 26-float2 rolling window spilled to scratch (WRITE_SIZE 46MB, FETCH +186MB,
// VALUBusy 39%). Cap 128 keeps the ~100-reg live set in RF; LDS 31.7KB still
// allows 4-5 blocks/CU at runtime.

namespace {
constexpr int IMG_H = 512, IMG_W = 512;
constexpr int OUT_H = 502, OUT_W = 502;
constexpr int NIMG  = 96;             // B*C
constexpr int RPB   = 32;             // output rows per block
constexpr int NBAND = 16;             // ceil(502/32)
constexpr int QR    = 3;              // output rows per inner iteration
constexpr int BUFW  = 528;            // 132 float4 slots (512 data + halo/pad)
constexpr int NTASK = NBAND * NIMG;   // 1536 blocks
constexpr double TOTAL = 24192384.0;  // 96*502*502

// exp(-k^2/4.5), double, normalized at compile time (absmax 0.0 in R1/R2/R3)
constexpr double U0 = 0.0038659201;
constexpr double U1 = 0.0285655007;
constexpr double U2 = 0.1353352832366127;
constexpr double U3 = 0.4111122898;
constexpr double U4 = 0.8007374026;
constexpr double SS = 1.0 + 2.0 * (U0 + U1 + U2 + U3 + U4);
}

__device__ __forceinline__ int sw(int c4) { return c4 ^ ((c4 >> 3) & 1); }

__device__ __forceinline__ float2 f2fma(float w, float2 a, float2 c) {
    return make_float2(fmaf(w, a.x, c.x), fmaf(w, a.y, c.y));
}

__global__ __launch_bounds__(256, 4) void ssim_main(const float* __restrict__ img1,
                                                    const float* __restrict__ img2,
                                                    float* __restrict__ partial)
{
    __shared__ __align__(16) float vrow[QR][5][BUFW];
    __shared__ float red[4];

    const float g[11] = {
        (float)(U0/SS), (float)(U1/SS), (float)(U2/SS), (float)(U3/SS), (float)(U4/SS),
        (float)(1.0/SS),
        (float)(U4/SS), (float)(U3/SS), (float)(U2/SS), (float)(U1/SS), (float)(U0/SS)
    };
    constexpr float C1 = 1e-4f, C2 = 9e-4f;

    const int t   = threadIdx.x;
    const int z   = blockIdx.y;
    const int oy0 = blockIdx.x * RPB;
    const int row_end = min(oy0 + RPB, OUT_H);

    const float* p1 = img1 + (size_t)z * (IMG_H * IMG_W);
    const float* p2 = img2 + (size_t)z * (IMG_H * IMG_W);

    // phase-V: thread owns input cols 2t, 2t+1
    const int woff = (sw(t >> 1) << 2) + ((t & 1) << 1);

    // phase-H: hq = row-in-group (t>>6, rows 0..2 active), 8-col group at cb
    const int hq = t >> 6;
    const int hl = t & 63;
    const int cb = hl << 3;
    int roff[5];
    #pragma unroll
    for (int k = 0; k < 5; ++k) roff[k] = sw((cb >> 2) + k) << 2;

    float local = 0.f;

    for (int r0 = oy0; r0 < row_end; r0 += QR) {
        // ------------- phase V: vertical 11-tap conv, registers -------------
        float2 xr[QR + 10], yr[QR + 10];
        #pragma unroll
        for (int j = 0; j < QR + 10; ++j) {
            int row = r0 + j;
            row = row < IMG_H ? row : IMG_H - 1;   // tail clamp; unused by valid outputs
            xr[j] = *(const float2*)(p1 + (size_t)row * IMG_W + 2 * t);
            yr[j] = *(const float2*)(p2 + (size_t)row * IMG_W + 2 * t);
        }
        float2 vm1[QR], vm2[QR], v11[QR], v22[QR], v12[QR];
        #pragma unroll
        for (int q = 0; q < QR; ++q) {
            vm1[q] = make_float2(0.f, 0.f); vm2[q] = make_float2(0.f, 0.f);
            v11[q] = make_float2(0.f, 0.f); v22[q] = make_float2(0.f, 0.f);
            v12[q] = make_float2(0.f, 0.f);
        }
        #pragma unroll
        for (int j = 0; j < QR + 10; ++j) {
            float2 x = xr[j], y = yr[j];
            float2 xx = make_float2(x.x * x.x, x.y * x.y);
            float2 yy = make_float2(y.x * y.x, y.y * y.y);
            float2 xy = make_float2(x.x * y.x, x.y * y.y);
            #pragma unroll
            for (int q = 0; q < QR; ++q) {
                int k = j - q;
                if (k >= 0 && k < 11) {
                    float w = g[k];
                    vm1[q] = f2fma(w, x,  vm1[q]);
                    vm2[q] = f2fma(w, y,  vm2[q]);
                    v11[q] = f2fma(w, xx, v11[q]);
                    v22[q] = f2fma(w, yy, v22[q]);
                    v12[q] = f2fma(w, xy, v12[q]);
                }
            }
        }
        __syncthreads();   // previous iteration's phase-H reads complete
        #pragma unroll
        for (int q = 0; q < QR; ++q) {
            *(float2*)&vrow[q][0][woff] = vm1[q];
            *(float2*)&vrow[q][1][woff] = vm2[q];
            *(float2*)&vrow[q][2][woff] = v11[q];
            *(float2*)&vrow[q][3][woff] = v22[q];
            *(float2*)&vrow[q][4][woff] = v12[q];
        }
        __syncthreads();

        // ------------- phase H: horizontal 11-tap conv + SSIM -------------
        const int rr = r0 + hq;
        if (hq < QR && rr < row_end && cb < OUT_W) {
            float aa[5][8];
            #pragma unroll
            for (int ch = 0; ch < 5; ++ch) {
                const float* bc = &vrow[hq][ch][0];
                float f[20];
                #pragma unroll
                for (int k = 0; k < 5; ++k) {
                    float4 v = *(const float4*)(bc + roff[k]);
                    f[4*k+0] = v.x; f[4*k+1] = v.y; f[4*k+2] = v.z; f[4*k+3] = v.w;
                }
                #pragma unroll
                for (int j = 0; j < 8; ++j) {
                    float s = 0.f;
                    #pragma unroll
                    for (int k = 0; k < 11; ++k) s = fmaf(g[k], f[j + k], s);
                    aa[ch][j] = s;
                }
            }
            #pragma unroll
            for (int j = 0; j < 8; ++j) {
                if (cb + j < OUT_W) {
                    float mu1 = aa[0][j], mu2 = aa[1][j];
                    float mu11 = mu1 * mu1, mu22 = mu2 * mu2, mu12 = mu1 * mu2;
                    float s1  = aa[2][j] - mu11;
                    float s2  = aa[3][j] - mu22;
                    float s12 = aa[4][j] - mu12;
                    float num = fmaf(2.f, mu12, C1) * fmaf(2.f, s12, C2);
                    float den = (mu11 + mu22 + C1) * (s1 + s2 + C2);
                    float rc  = __builtin_amdgcn_rcpf(den);
                    rc = rc * fmaf(-den, rc, 2.f);          // one Newton step
                    local += num * rc;
                }
            }
        }
    }

    // ---------- reduction: wave shuffle -> LDS -> one store per block ----------
    #pragma unroll
    for (int off = 32; off > 0; off >>= 1) local += __shfl_down(local, off, 64);
    if ((t & 63) == 0) red[t >> 6] = local;
    __syncthreads();
    if (t == 0)
        partial[blockIdx.y * NBAND + blockIdx.x] = red[0] + red[1] + red[2] + red[3];
}

__global__ void ssim_fin(const float* __restrict__ partial, float* __restrict__ out)
{
    __shared__ double sd[256];
    double sum = 0.0;
    for (int i = threadIdx.x; i < NTASK; i += 256) sum += (double)partial[i];
    sd[threadIdx.x] = sum;
    __syncthreads();
    for (int w = 128; w > 0; w >>= 1) {
        if (threadIdx.x < w) sd[threadIdx.x] += sd[threadIdx.x + w];
        __syncthreads();
    }
    if (threadIdx.x == 0) out[0] = (float)(sd[0] / TOTAL);
}

extern "C" void kernel_launch(void* const* d_in, const int* in_sizes, int n_in,
                              void* d_out, int out_size, void* d_ws, size_t ws_size,
                              hipStream_t stream)
{
    (void)in_sizes; (void)n_in; (void)out_size; (void)ws_size;
    const float* img1 = (const float*)d_in[0];
    const float* img2 = (const float*)d_in[1];
    float* partial = (float*)d_ws;

    hipLaunchKernelGGL(ssim_main, dim3(NBAND, NIMG), dim3(256), 0, stream,
                       img1, img2, partial);
    hipLaunchKernelGGL(ssim_fin, dim3(1), dim3(256), 0, stream,
                       partial, (float*)d_out);
}